// Round 7
// baseline (111.492 us; speedup 1.0000x reference)
//
#include <hip/hip_runtime.h>

// Event-to-image: B=16, N=500000 events (t,x,y,p) f32 -> (16,720,1280,3) f32.
// Last-event-wins per pixel: p==1 -> (0,255,255); p==0 -> (255,0,255);
// untouched -> (255,255,510). Order-independent via max over
// key = ((event_idx+1)<<1)|p, packed pk = x<<20 | key (31 bits).
//
// R7: single-global-read scatter. R6 scatter (~75us of 97.8) was latency-bound
// (VALUBusy 3%, 16 waves/CU) and touched the event stream twice. Now pass 1
// packs (y,x,p) into a 32KB LDS cache (one nt global read), pass 2 ranks from
// LDS and stores pk directly into the block's own 32KB bins chunk (L2-resident,
// fully dirtied -> no RMW inflation). stage[] and its copy-out are gone.
// 512-thread blocks: 38.5KB LDS -> 4 blocks/CU x 8 waves = 32 waves/CU (2x R6).

#define WIDTH   1280
#define HEIGHT  720
#define BATCH   16
#define NEV     500000
#define THREADS 512
#define EPT     16
#define EVPB    (THREADS * EPT)             // 8192 events per block
#define BPB     ((NEV + EVPB - 1) / EVPB)   // 62 blocks per batch
#define NBLK    (BATCH * BPB)               // 992
#define PH      (HEIGHT + 1)                // 721 prefix entries per block

typedef float f4 __attribute__((ext_vector_type(4)));

// ws layout: [0, NBLK*PH*4)=pref_g (2.86 MB); [0x400000, +NBLK*EVPB*4)=bins (32.5 MB)

__global__ __launch_bounds__(THREADS, 8) void scatter_k(const float4* __restrict__ ev,
                                                        unsigned int* __restrict__ pref_g,
                                                        unsigned int* __restrict__ bins) {
    __shared__ unsigned int hist[HEIGHT];
    __shared__ unsigned int offs[HEIGHT];
    __shared__ unsigned int wtot[8];
    __shared__ unsigned int cache[EVPB];     // 32 KB: y<<12 | x<<1 | p

    int t = threadIdx.x;
    int batch = blockIdx.x / BPB;
    int blk   = blockIdx.x % BPB;
    int ev0   = blk * EVPB;
    int cnt   = NEV - ev0; if (cnt > EVPB) cnt = EVPB;
    const f4* bev = (const f4*)(ev + (size_t)batch * NEV + ev0);

    for (int r = t; r < HEIGHT; r += THREADS) hist[r] = 0u;
    __syncthreads();

    // pass 1: ONE global read (nontemporal), pack into LDS, histogram
    for (int k = 0; k < EPT; ++k) {
        int e = t + k * THREADS;
        if (e < cnt) {
            f4 v = __builtin_nontemporal_load(&bev[e]);
            unsigned int yi = (unsigned int)(int)v.z;
            unsigned int xi = (unsigned int)(int)v.y;
            unsigned int pb = (v.w == 1.0f) ? 1u : 0u;
            cache[e] = (yi << 12) | (xi << 1) | pb;
            atomicAdd(&hist[yi], 1u);
        }
    }
    __syncthreads();

    // exclusive prefix over 720 rows: threads 0..239 own 3 rows; shfl wave scan
    unsigned int own = 0u;
    int b3 = t * 3;
    if (t < 240) own = hist[b3] + hist[b3 + 1] + hist[b3 + 2];
    unsigned int incl = own;
    for (int d = 1; d < 64; d <<= 1) {
        unsigned int n = __shfl_up(incl, d);
        if ((t & 63) >= d) incl += n;
    }
    if ((t & 63) == 63) wtot[t >> 6] = incl;
    __syncthreads();
    unsigned int wbase = 0u;
    for (int w = 0; w < (t >> 6); ++w) wbase += wtot[w];
    unsigned int total = 0u;
    for (int w = 0; w < 8; ++w) total += wtot[w];     // == cnt (waves 4-7 add 0)
    if (t < 240) {
        unsigned int run = wbase + incl - own;
        offs[b3] = run;      run += hist[b3];
        offs[b3 + 1] = run;  run += hist[b3 + 1];
        offs[b3 + 2] = run;
    }
    __syncthreads();

    // publish per-block row prefix BEFORE pass 2 mutates offs
    unsigned int* pg = pref_g + (size_t)blockIdx.x * PH;
    for (int r = t; r < PH; r += THREADS)
        pg[r] = (r < HEIGHT) ? offs[r] : total;
    __syncthreads();

    // pass 2: rank from LDS, store pk straight to this block's 32KB chunk
    unsigned int* chunk = bins + (size_t)blockIdx.x * EVPB;
    for (int k = 0; k < EPT; ++k) {
        int e = t + k * THREADS;
        if (e < cnt) {
            unsigned int c  = cache[e];
            unsigned int yi = c >> 12;
            unsigned int slot = atomicAdd(&offs[yi], 1u);
            // pk = x<<20 | ((idx+1)<<1) | p ; x = (c>>1)&0x7FF -> (c&0xFFE)<<19
            unsigned int pk = ((c & 0xFFEu) << 19)
                            | (((unsigned int)(ev0 + e) + 1u) << 1) | (c & 1u);
            chunk[slot] = pk;
        }
    }
}

__global__ __launch_bounds__(256) void render_k(const unsigned int* __restrict__ pref_g,
                                                const unsigned int* __restrict__ bins,
                                                float4* __restrict__ out) {
    __shared__ unsigned int win[WIDTH];
    __shared__ unsigned int segbase[BPB];
    __shared__ unsigned int segpref[65];

    int t = threadIdx.x;
    int rowid = blockIdx.x;                  // batch*720 + y
    int batch = rowid / HEIGHT;
    int r     = rowid - batch * HEIGHT;

    for (int x = t; x < WIDTH; x += 256) win[x] = 0u;

    unsigned int mycnt = 0u;
    if (t < BPB) {
        const unsigned int* pg = pref_g + (size_t)(batch * BPB + t) * PH + r;
        unsigned int p0 = pg[0], p1 = pg[1];
        segbase[t] = (unsigned int)((batch * BPB + t) * EVPB) + p0;
        mycnt = p1 - p0;
    }
    if (t < 64) {                            // wave-0 inclusive scan of 62 counts
        unsigned int v = mycnt;
        for (int d = 1; d < 64; d <<= 1) {
            unsigned int n = __shfl_up(v, d);
            if (t >= d) v += n;
        }
        if (t == 0) segpref[0] = 0u;
        segpref[t + 1] = v;
    }
    __syncthreads();

    unsigned int total = segpref[BPB];       // ~694
    for (unsigned int j = t; j < total; j += 256) {
        int lo = 0, hi = BPB - 1;            // largest s with segpref[s] <= j
        while (lo < hi) {
            int mid = (lo + hi + 1) >> 1;
            if (segpref[mid] <= j) lo = mid; else hi = mid - 1;
        }
        unsigned int pk = bins[segbase[lo] + (j - segpref[lo])];
        atomicMax(&win[pk >> 20], pk & 0xFFFFFu);   // LDS atomic
    }
    __syncthreads();

    // write one image row: 1280 px * 3 ch = 960 float4, coalesced, nontemporal
    f4* orow = (f4*)(out + (size_t)rowid * (WIDTH * 3 / 4));
    for (int j = t; j < WIDTH * 3 / 4; j += 256) {
        float vals[4];
#pragma unroll
        for (int c = 0; c < 4; ++c) {
            int fi = j * 4 + c;
            int px = fi / 3;
            int ch = fi - px * 3;
            unsigned int k = win[px];
            float val;
            if (k == 0u) val = (ch == 2) ? 510.0f : 255.0f;
            else if (ch == 2) val = 255.0f;
            else if (ch == 0) val = (k & 1u) ? 0.0f : 255.0f;
            else              val = (k & 1u) ? 255.0f : 0.0f;
            vals[c] = val;
        }
        f4 o = { vals[0], vals[1], vals[2], vals[3] };
        __builtin_nontemporal_store(o, orow + j);
    }
}

extern "C" void kernel_launch(void* const* d_in, const int* in_sizes, int n_in,
                              void* d_out, int out_size, void* d_ws, size_t ws_size,
                              hipStream_t stream) {
    const float4* ev = (const float4*)d_in[0];
    unsigned int* pref_g = (unsigned int*)d_ws;
    unsigned int* bins   = (unsigned int*)((char*)d_ws + 0x400000);
    float4* out = (float4*)d_out;

    scatter_k<<<NBLK, THREADS, 0, stream>>>(ev, pref_g, bins);
    render_k<<<BATCH * HEIGHT, 256, 0, stream>>>(pref_g, bins, out);
}